// Round 9
// baseline (1365.678 us; speedup 1.0000x reference)
//
#include <hip/hip_runtime.h>

// SparseFinerAttention on MI355X — round 8 (split pipeline: qk_exp -> select -> masked PV)
// B=2 N=4096 C=768 H=12 D=64 SCALE=1/8 K_keep=409
//
// cast->fp16; Q/K/V NT-GEMMs; then per bh-chunk:
//   A qk_exp:      P~[row][key] = fp16(exp(min(qk,11))), coalesced via LDS bounce
//   B select_rows: 1 wave/row: SWAR binary search -> {t, c*, invZ} (16B/row)
//                  keep semantics: x >= t + (idx > c*)  (exact ties by index)
//   C pv_masked:   register-only PV GEMM, in-register SWAR masking, invZ epilogue
// final projection GEMM + bias.

typedef unsigned short u16;
typedef unsigned int   u32;
typedef float    f32x4 __attribute__((ext_vector_type(4)));
typedef _Float16 f16x8 __attribute__((ext_vector_type(8)));
typedef u16      u16x8 __attribute__((ext_vector_type(8)));
typedef u16      u16x4 __attribute__((ext_vector_type(4)));
typedef u32      u32x4 __attribute__((ext_vector_type(4)));

#define NHEADS 12
#define SEQ    4096
#define DIMC   768
#define HDIM   64
#define KKEEP  409

__device__ __forceinline__ f32x4 mfma16(f16x8 a, f16x8 b, f32x4 c) {
  return __builtin_amdgcn_mfma_f32_16x16x32_f16(a, b, c, 0, 0, 0);
}
__device__ __forceinline__ u16 f2h_bits(float f) {
  return __builtin_bit_cast(u16, (_Float16)f);
}
__device__ __forceinline__ float h2f_bits(u16 b) {
  return (float)__builtin_bit_cast(_Float16, b);
}

// GPUOpen canonical wave64 DPP reductions (verified bit-correct in round 6).
__device__ __forceinline__ u32 wred_add_u32(u32 x) {
  x += (u32)__builtin_amdgcn_update_dpp(0, (int)x, 0x111, 0xF, 0xF, true);
  x += (u32)__builtin_amdgcn_update_dpp(0, (int)x, 0x112, 0xF, 0xF, true);
  x += (u32)__builtin_amdgcn_update_dpp(0, (int)x, 0x114, 0xF, 0xF, true);
  x += (u32)__builtin_amdgcn_update_dpp(0, (int)x, 0x118, 0xF, 0xF, true);
  x += (u32)__builtin_amdgcn_update_dpp(0, (int)x, 0x142, 0xF, 0xF, true);
  x += (u32)__builtin_amdgcn_update_dpp(0, (int)x, 0x143, 0xF, 0xF, true);
  return (u32)__builtin_amdgcn_readlane((int)x, 63);
}
__device__ __forceinline__ float wred_add_f32(float x) {
#define _DPPF(ctrl) x += __builtin_bit_cast(float, __builtin_amdgcn_update_dpp( \
      0, __builtin_bit_cast(int, x), ctrl, 0xF, 0xF, true));
  _DPPF(0x111) _DPPF(0x112) _DPPF(0x114) _DPPF(0x118) _DPPF(0x142) _DPPF(0x143)
#undef _DPPF
  return __builtin_bit_cast(float, __builtin_amdgcn_readlane(__builtin_bit_cast(int, x), 63));
}
__device__ __forceinline__ u32 wred_min_u32(u32 x) {
#define _DPPM(ctrl) { u32 y = (u32)__builtin_amdgcn_update_dpp((int)0xFFFFFFFF, (int)x, ctrl, 0xF, 0xF, false); \
                      x = x < y ? x : y; }
  _DPPM(0x111) _DPPM(0x112) _DPPM(0x114) _DPPM(0x118) _DPPM(0x142) _DPPM(0x143)
#undef _DPPM
  return (u32)__builtin_amdgcn_readlane((int)x, 63);
}

// ---------------- cast fp32 -> fp16 (vectorized) ----------------
__global__ __launch_bounds__(256) void cast_f32_to_f16(const float* __restrict__ in,
                                                       u16* __restrict__ out, int n4) {
  int i = blockIdx.x * 256 + threadIdx.x;
  if (i >= n4) return;
  float4 v = ((const float4*)in)[i];
  u16x4 o;
  o[0] = f2h_bits(v.x); o[1] = f2h_bits(v.y); o[2] = f2h_bits(v.z); o[3] = f2h_bits(v.w);
  ((u16x4*)out)[i] = o;
}

// ---------------- NT GEMM: C[M][768] = A[M][768] @ B[768][768]^T ----------------
template<int MODE>
__global__ __launch_bounds__(256) void gemm_nt(const u16* __restrict__ A, const u16* __restrict__ B,
                                               float scale, const float* __restrict__ bias,
                                               void* __restrict__ dstv) {
  __shared__ __align__(16) u16 As[128 * 64];
  __shared__ __align__(16) u16 Bs[128 * 64];
  const int tid  = threadIdx.x;
  const int lane = tid & 63, wave = tid >> 6;
  const int l15 = lane & 15, l4 = lane >> 4;
  const int row0 = blockIdx.x * 128, col0 = blockIdx.y * 128;
  const int wr = (wave >> 1) * 64, wc = (wave & 1) * 64;
  f32x4 acc[4][4];
#pragma unroll
  for (int i = 0; i < 4; i++)
#pragma unroll
    for (int j = 0; j < 4; j++) acc[i][j] = f32x4{0.f, 0.f, 0.f, 0.f};

  for (int k0 = 0; k0 < DIMC; k0 += 64) {
#pragma unroll
    for (int i = 0; i < 4; i++) {
      int id = tid + i * 256;
      int r = id >> 3, c = id & 7;
      f16x8 va = *(const f16x8*)(A + (size_t)(row0 + r) * DIMC + k0 + c * 8);
      f16x8 vb = *(const f16x8*)(B + (size_t)(col0 + r) * DIMC + k0 + c * 8);
      *(f16x8*)(As + r * 64 + ((c ^ (r & 7)) << 3)) = va;
      *(f16x8*)(Bs + r * 64 + ((c ^ (r & 7)) << 3)) = vb;
    }
    __syncthreads();
#pragma unroll
    for (int ks = 0; ks < 2; ++ks) {
      f16x8 af[4], bfr[4];
#pragma unroll
      for (int i = 0; i < 4; i++) {
        int r = wr + i * 16 + l15;
        int c = ks * 4 + l4;
        af[i] = *(const f16x8*)(As + r * 64 + ((c ^ (r & 7)) << 3));
        int r2 = wc + i * 16 + l15;
        bfr[i] = *(const f16x8*)(Bs + r2 * 64 + ((c ^ (r2 & 7)) << 3));
      }
#pragma unroll
      for (int i = 0; i < 4; i++)
#pragma unroll
        for (int j = 0; j < 4; j++) acc[i][j] = mfma16(af[i], bfr[j], acc[i][j]);
    }
    __syncthreads();
  }

#pragma unroll
  for (int i = 0; i < 4; i++) {
#pragma unroll
    for (int j = 0; j < 4; j++) {
      int rowb = row0 + wr + i * 16 + (l4 << 2);
      int col  = col0 + wc + j * 16 + l15;
      if (MODE == 2) {
        float* dst = (float*)dstv;
        float bv = bias[col];
#pragma unroll
        for (int jj = 0; jj < 4; jj++)
          dst[(size_t)(rowb + jj) * DIMC + col] = acc[i][j][jj] + bv;
      } else if (MODE == 0) {
        u16* dst = (u16*)dstv;
        int hh = col >> 6, d = col & 63;
#pragma unroll
        for (int jj = 0; jj < 4; jj++) {
          int row = rowb + jj;
          int bb = row >> 12, n = row & 4095;
          dst[(((size_t)bb * NHEADS + hh) * SEQ + n) * HDIM + d] = f2h_bits(acc[i][j][jj] * scale);
        }
      } else { // MODE 1: V transposed [b][h][d][n]
        u16* dst = (u16*)dstv;
        int hh = col >> 6, d = col & 63;
        int bb = rowb >> 12, nb = rowb & 4095;
        u16x4 pack;
#pragma unroll
        for (int jj = 0; jj < 4; jj++) pack[jj] = f2h_bits(acc[i][j][jj] * scale);
        *(u16x4*)(dst + (((size_t)bb * NHEADS + hh) * HDIM + d) * SEQ + nb) = pack;
      }
    }
  }
}

// ---------------- A: P~ = fp16(exp(min(QK^T,11))) ----------------
// grid (32 qrowtiles, 32 keytiles, nbh), 256 thr. Wave: 32 qrows x 128 keys.
// Swapped mfma(K,Q): lane holds 4 consecutive keys of one qrow -> LDS bounce ->
// fully coalesced 16B row-major global stores.
__global__ __launch_bounds__(256) void qk_exp(const u16* __restrict__ Q, const u16* __restrict__ K,
                                              u16* __restrict__ P, int bh0) {
  __shared__ __align__(16) u16 bounce[4][32 * 128];   // 8 KB/wave, 16B-granule XOR swizzle
  const int tid = threadIdx.x, lane = tid & 63, wave = tid >> 6;
  const int l15 = lane & 15, l4 = lane >> 4;
  const size_t bhg = (size_t)bh0 + blockIdx.z;
  const int q0 = blockIdx.x * 128 + wave * 32;
  const int k0 = blockIdx.y * 128;
  const u16* Qh = Q + (bhg * SEQ + q0) * HDIM;
  const u16* Kh = K + (bhg * SEQ + k0) * HDIM;

  f16x8 qf[2][2];   // [16-qrow group][k-half]; Q pre-scaled by 1/8
#pragma unroll
  for (int qr = 0; qr < 2; ++qr)
#pragma unroll
    for (int kh = 0; kh < 2; ++kh)
      qf[qr][kh] = *(const f16x8*)(Qh + (qr * 16 + l15) * HDIM + kh * 32 + l4 * 8);

  u16* bw = bounce[wave];
#pragma unroll 2
  for (int ks = 0; ks < 8; ++ks) {
    const u16* kp = Kh + (size_t)(ks * 16 + l15) * HDIM + l4 * 8;
    f16x8 kf0 = *(const f16x8*)kp;
    f16x8 kf1 = *(const f16x8*)(kp + 32);
#pragma unroll
    for (int qr = 0; qr < 2; ++qr) {
      f32x4 acc = f32x4{0.f, 0.f, 0.f, 0.f};
      acc = mfma16(kf0, qf[qr][0], acc);
      acc = mfma16(kf1, qf[qr][1], acc);
      int row = qr * 16 + l15;                 // qrow within wave's 32
      int gran = ks * 2 + (l4 >> 1);           // 8-key granule 0..15
      u16x4 pack;
#pragma unroll
      for (int j = 0; j < 4; j++) pack[j] = f2h_bits(__expf(fminf(acc[j], 11.0f)));
      *(u16x4*)(bw + row * 128 + ((gran ^ (row & 7)) << 3) + ((l4 & 1) << 2)) = pack;
    }
  }
  __syncthreads();
#pragma unroll
  for (int R = 0; R < 8; ++R) {
    int row = R * 4 + (lane >> 4);
    int gran = lane & 15;
    f16x8 v = *(const f16x8*)(bw + row * 128 + ((gran ^ (row & 7)) << 3));
    *(f16x8*)(P + ((size_t)blockIdx.z * SEQ + q0 + row) * SEQ + k0 + gran * 8) = v;
  }
}

// ---------------- B: per-row exact top-k(409) -> {t, c*, invZ} ----------------
// 1 wave per row; keys = positive fp16 exp bits (order-preserving u16).
// c* = global index of the r-th ==t key (index order) => stateless masking downstream.
__global__ __launch_bounds__(512) void select_rows(const u16* __restrict__ P, u32* __restrict__ meta) {
  const int tid = threadIdx.x, lane = tid & 63, wave = tid >> 6;
  const size_t row = (size_t)blockIdx.x * 8 + wave;
  const u16* Pr = P + row * SEQ;
  const u32 H = 0x80008000u;
  u32 X[8][4];
#pragma unroll
  for (int cc = 0; cc < 8; ++cc) {
    u32x4 v = *(const u32x4*)(Pr + cc * 512 + lane * 8);
#pragma unroll
    for (int p = 0; p < 4; p++) X[cc][p] = v[p] | H;
  }
  // Z = sum of all exp values (f32)
  float z = 0.f;
#pragma unroll
  for (int cc = 0; cc < 8; ++cc)
#pragma unroll
    for (int p = 0; p < 4; p++) {
      u32 x = X[cc][p];
      z += h2f_bits((u16)(x & 0x7FFFu));
      z += h2f_bits((u16)((x >> 16) & 0x7FFFu));
    }
  z = wred_add_f32(z);
  float invZ = 1.f / z;
  // binary search: t = smallest v with count(key > v) < KKEEP
  u32 lo = 0, hi = 0x7FFFu, c1 = 0;
  while (lo < hi) {
    u32 mid = (lo + hi) >> 1;
    u32 M1 = (mid + 1) * 0x10001u;
    u32 pc = 0;
#pragma unroll
    for (int cc = 0; cc < 8; ++cc)
#pragma unroll
      for (int p = 0; p < 4; p++) {
        u32 d = X[cc][p] - M1;
        pc += (d & H) >> 15;
      }
    u32 s = wred_add_u32(pc);
    u32 cnt = (s & 0xFFFFu) + (s >> 16);
    if (cnt < KKEEP) { hi = mid; c1 = cnt; } else lo = mid + 1;
  }
  const u32 t = lo;
  const int r = KKEEP - (int)c1;               // ties kept, r >= 1
  // find c* = index of the r-th ==t key in row order
  const u32 M1t = (t + 1) * 0x10001u;
  const u32 M0t = t * 0x10001u;
  int run = 0; u32 cstar = 0;
  for (int cc = 0; cc < 8; ++cc) {
    u32 eqm[4]; u32 s = 0;
#pragma unroll
    for (int p = 0; p < 4; p++) {
      u32 x = X[cc][p];
      u32 g1 = (x - M1t) & H;
      u32 g0 = (x - M0t) & H;
      eqm[p] = g0 ^ g1;
      s += eqm[p] >> 15;
    }
    int ec = (int)((s & 0xFFFFu) + (s >> 16));
    int inc = ec;
#pragma unroll
    for (int o = 1; o < 64; o <<= 1) { int pf = __shfl_up(inc, o); if (lane >= o) inc += pf; }
    int tot = __shfl(inc, 63);
    if (run + tot >= r) {                       // uniform: boundary chunk
      int need = r - run;
      int local = need - (inc - ec);            // 1..ec iff this lane owns it
      u32 cand = 0xFFFFFFFFu; int cnt2 = 0;
#pragma unroll
      for (int p = 0; p < 4; p++)
#pragma unroll
        for (int half = 0; half < 2; half++) {
          u32 eq = half ? (eqm[p] >> 31) : ((eqm[p] >> 15) & 1u);
          if (eq) { cnt2++; if (cnt2 == local) cand = (u32)(cc * 512 + lane * 8 + p * 2 + half); }
        }
      cstar = wred_min_u32(cand);
      break;
    }
    run += tot;
  }
  if (lane == 0) {
    u32x4 m; m[0] = t; m[1] = cstar; m[2] = __builtin_bit_cast(u32, invZ); m[3] = 0;
    *(u32x4*)(meta + row * 4) = m;
  }
}

// ---------------- C: masked PV, register-only ----------------
// grid (64 rowtiles, nbh), 256 thr; wave: 16 P-rows x 64 dims, k-loop 128 iters.
// keep(x, idx) = x >= t + (idx > c*)  -> SWAR per u32 pair. invZ in epilogue.
__global__ __launch_bounds__(256) void pv_masked(const u16* __restrict__ P, const u32* __restrict__ meta,
                                                 const u16* __restrict__ Vt, u16* __restrict__ Ob, int bh0) {
  const int tid = threadIdx.x, lane = tid & 63, wave = tid >> 6;
  const int l15 = lane & 15, l4 = lane >> 4;
  const int bhl = blockIdx.y;
  const int bhg = bh0 + bhl;
  const int b = bhg / NHEADS, h = bhg - b * NHEADS;
  const int rowl = blockIdx.x * 64 + wave * 16 + l15;          // n index
  const u32* mp = meta + ((size_t)bhl * SEQ + rowl) * 4;
  const u32 t = mp[0];
  const int cstar = (int)mp[1];
  const float invZ = __builtin_bit_cast(float, mp[2]);
  const u32 Mt = t * 0x10001u;
  const u32 H = 0x80008000u;
  const u16* Prow = P + ((size_t)bhl * SEQ + rowl) * SEQ + l4 * 8;
  const u16* Vh = Vt + (size_t)bhg * HDIM * SEQ;

  f32x4 acc[4];
#pragma unroll
  for (int ds = 0; ds < 4; ds++) acc[ds] = f32x4{0.f, 0.f, 0.f, 0.f};

#pragma unroll 2
  for (int kb = 0; kb < SEQ; kb += 32) {
    u32x4 praw = *(const u32x4*)(Prow + kb);
    int base = cstar - (kb + l4 * 8);
    u32x4 om;
#pragma unroll
    for (int p = 0; p < 4; ++p) {
      u32 s0 = (u32)(base - 2 * p) >> 31;        // idx0 > c*
      u32 s1 = (u32)(base - 2 * p - 1) >> 31;    // idx1 > c*
      u32 M1 = Mt + s0 + (s1 << 16);             // per-half threshold t + pos
      u32 d  = (praw[p] | H) - M1;
      u32 g  = d & H;                             // bit15/31: x >= t + pos
      u32 m  = g | (g - (g >> 15));               // 0x8000-bit -> 0xFFFF
      om[p]  = praw[p] & m;
    }
    f16x8 pb = __builtin_bit_cast(f16x8, om);
#pragma unroll
    for (int ds = 0; ds < 4; ++ds) {
      f16x8 af = *(const f16x8*)(Vh + (size_t)(ds * 16 + l15) * SEQ + kb + l4 * 8);
      acc[ds] = mfma16(af, pb, acc[ds]);          // D[vdim][prow]: col l15 = prow
    }
  }
  // epilogue: lane col = l15 = P-row (matches this lane's t/c*/invZ), rows = vdims
#pragma unroll
  for (int ds = 0; ds < 4; ++ds) {
    u16x4 pack;
#pragma unroll
    for (int j = 0; j < 4; j++) pack[j] = f2h_bits(acc[ds][j] * invZ);
    *(u16x4*)(Ob + ((size_t)b * SEQ + rowl) * DIMC + h * HDIM + ds * 16 + l4 * 4) = pack;
  }
}

// ---------------- launch ----------------
extern "C" void kernel_launch(void* const* d_in, const int* in_sizes, int n_in,
                              void* d_out, int out_size, void* d_ws, size_t ws_size,
                              hipStream_t stream) {
  const float* x  = (const float*)d_in[0];
  const float* Wq = (const float*)d_in[1];
  const float* Wk = (const float*)d_in[2];
  const float* Wv = (const float*)d_in[3];
  const float* Wp = (const float*)d_in[4];
  const float* bp = (const float*)d_in[5];
  float* out = (float*)d_out;

  const size_t M = 2 * (size_t)SEQ;            // 8192
  const size_t XB = M * DIMC * 2;
  const size_t WB = (size_t)DIMC * DIMC * 2;
  const size_t NBH = 2 * NHEADS;               // 24

  char* w = (char*)d_ws;
  u16* xb   = (u16*)w; w += XB;
  u16* Wqb  = (u16*)w; w += WB;
  u16* Wkb  = (u16*)w; w += WB;
  u16* Wvb  = (u16*)w; w += WB;
  u16* Wpb  = (u16*)w; w += WB;
  u16* Qb   = (u16*)w; w += XB;
  u16* Kbuf = (u16*)w; w += XB;
  u16* Vtb  = (u16*)w; w += XB;
  u16* Obuf = (u16*)w; w += XB;
  u32* meta = (u32*)w; w += NBH * SEQ * 16;    // {t, c*, invZ, pad} per row
  u16* Pbuf = (u16*)w;

  size_t used  = (size_t)(w - (char*)d_ws);
  size_t avail = ws_size > used ? ws_size - used : 0;
  const size_t perBh = (size_t)SEQ * SEQ * 2;  // 33.55 MB
  int chunk = (int)(avail / perBh);
  if (chunk > (int)NBH) chunk = (int)NBH;
  if (chunk < 1) chunk = 1;

  cast_f32_to_f16<<<6144, 256, 0, stream>>>(x,  xb,  (int)(M * DIMC / 4));
  cast_f32_to_f16<<<576,  256, 0, stream>>>(Wq, Wqb, (int)(WB / 8));
  cast_f32_to_f16<<<576,  256, 0, stream>>>(Wk, Wkb, (int)(WB / 8));
  cast_f32_to_f16<<<576,  256, 0, stream>>>(Wv, Wvb, (int)(WB / 8));
  cast_f32_to_f16<<<576,  256, 0, stream>>>(Wp, Wpb, (int)(WB / 8));

  dim3 gg(64, 6);
  gemm_nt<0><<<gg, 256, 0, stream>>>(xb, Wqb, 0.125f, nullptr, Qb);    // Q pre-scaled
  gemm_nt<0><<<gg, 256, 0, stream>>>(xb, Wkb, 1.0f,   nullptr, Kbuf);
  gemm_nt<1><<<gg, 256, 0, stream>>>(xb, Wvb, 1.0f,   nullptr, Vtb);   // V transposed

  for (int bh0 = 0; bh0 < (int)NBH; bh0 += chunk) {
    int nb = (int)NBH - bh0; if (nb > chunk) nb = chunk;
    qk_exp     <<<dim3(32, 32, nb), 256, 0, stream>>>(Qb, Kbuf, Pbuf, bh0);
    select_rows<<<dim3(nb * 512),   512, 0, stream>>>(Pbuf, meta);
    pv_masked  <<<dim3(64, nb),     256, 0, stream>>>(Pbuf, meta, Vtb, Obuf, bh0);
  }

  gemm_nt<2><<<gg, 256, 0, stream>>>(Obuf, Wpb, 1.0f, bp, out);
}

// Round 10
// 1086.179 us; speedup vs baseline: 1.2573x; 1.2573x over previous
//
#include <hip/hip_runtime.h>

// SparseFinerAttention on MI355X — round 9 (split: qk_exp -> fused select+PV, high occupancy)
// B=2 N=4096 C=768 H=12 D=64 SCALE=1/8 K_keep=409
//
// cast->fp16; Q/K/V NT-GEMMs; per bh-chunk (P~ sized to fit workspace/L3):
//   A qk_exp:    P~[row][key] = fp16(exp(min(qk,11))), coalesced via LDS bounce
//   B pv_select: block=16 rows, 8 waves. Phase1: SWAR top-k per row -> {t,c*,invZ} in LDS.
//                Phase2: key-split masked PV (in-register SWAR mask), LDS f32 reduce.
// final projection GEMM + bias.

typedef unsigned short u16;
typedef unsigned int   u32;
typedef float    f32x4 __attribute__((ext_vector_type(4)));
typedef _Float16 f16x8 __attribute__((ext_vector_type(8)));
typedef u16      u16x8 __attribute__((ext_vector_type(8)));
typedef u16      u16x4 __attribute__((ext_vector_type(4)));
typedef u32      u32x4 __attribute__((ext_vector_type(4)));

#define NHEADS 12
#define SEQ    4096
#define DIMC   768
#define HDIM   64
#define KKEEP  409

__device__ __forceinline__ f32x4 mfma16(f16x8 a, f16x8 b, f32x4 c) {
  return __builtin_amdgcn_mfma_f32_16x16x32_f16(a, b, c, 0, 0, 0);
}
__device__ __forceinline__ u16 f2h_bits(float f) {
  return __builtin_bit_cast(u16, (_Float16)f);
}
__device__ __forceinline__ float h2f_bits(u16 b) {
  return (float)__builtin_bit_cast(_Float16, b);
}

// GPUOpen canonical wave64 DPP reductions (bit-correct since round 6).
__device__ __forceinline__ u32 wred_add_u32(u32 x) {
  x += (u32)__builtin_amdgcn_update_dpp(0, (int)x, 0x111, 0xF, 0xF, true);
  x += (u32)__builtin_amdgcn_update_dpp(0, (int)x, 0x112, 0xF, 0xF, true);
  x += (u32)__builtin_amdgcn_update_dpp(0, (int)x, 0x114, 0xF, 0xF, true);
  x += (u32)__builtin_amdgcn_update_dpp(0, (int)x, 0x118, 0xF, 0xF, true);
  x += (u32)__builtin_amdgcn_update_dpp(0, (int)x, 0x142, 0xF, 0xF, true);
  x += (u32)__builtin_amdgcn_update_dpp(0, (int)x, 0x143, 0xF, 0xF, true);
  return (u32)__builtin_amdgcn_readlane((int)x, 63);
}
__device__ __forceinline__ float wred_add_f32(float x) {
#define _DPPF(ctrl) x += __builtin_bit_cast(float, __builtin_amdgcn_update_dpp( \
      0, __builtin_bit_cast(int, x), ctrl, 0xF, 0xF, true));
  _DPPF(0x111) _DPPF(0x112) _DPPF(0x114) _DPPF(0x118) _DPPF(0x142) _DPPF(0x143)
#undef _DPPF
  return __builtin_bit_cast(float, __builtin_amdgcn_readlane(__builtin_bit_cast(int, x), 63));
}
__device__ __forceinline__ u32 wred_min_u32(u32 x) {
#define _DPPM(ctrl) { u32 y = (u32)__builtin_amdgcn_update_dpp((int)0xFFFFFFFF, (int)x, ctrl, 0xF, 0xF, false); \
                      x = x < y ? x : y; }
  _DPPM(0x111) _DPPM(0x112) _DPPM(0x114) _DPPM(0x118) _DPPM(0x142) _DPPM(0x143)
#undef _DPPM
  return (u32)__builtin_amdgcn_readlane((int)x, 63);
}

// ---------------- cast fp32 -> fp16 (vectorized) ----------------
__global__ __launch_bounds__(256) void cast_f32_to_f16(const float* __restrict__ in,
                                                       u16* __restrict__ out, int n4) {
  int i = blockIdx.x * 256 + threadIdx.x;
  if (i >= n4) return;
  float4 v = ((const float4*)in)[i];
  u16x4 o;
  o[0] = f2h_bits(v.x); o[1] = f2h_bits(v.y); o[2] = f2h_bits(v.z); o[3] = f2h_bits(v.w);
  ((u16x4*)out)[i] = o;
}

// ---------------- NT GEMM: C[M][768] = A[M][768] @ B[768][768]^T ----------------
template<int MODE>
__global__ __launch_bounds__(256) void gemm_nt(const u16* __restrict__ A, const u16* __restrict__ B,
                                               float scale, const float* __restrict__ bias,
                                               void* __restrict__ dstv) {
  __shared__ __align__(16) u16 As[128 * 64];
  __shared__ __align__(16) u16 Bs[128 * 64];
  const int tid  = threadIdx.x;
  const int lane = tid & 63, wave = tid >> 6;
  const int l15 = lane & 15, l4 = lane >> 4;
  const int row0 = blockIdx.x * 128, col0 = blockIdx.y * 128;
  const int wr = (wave >> 1) * 64, wc = (wave & 1) * 64;
  f32x4 acc[4][4];
#pragma unroll
  for (int i = 0; i < 4; i++)
#pragma unroll
    for (int j = 0; j < 4; j++) acc[i][j] = f32x4{0.f, 0.f, 0.f, 0.f};

  for (int k0 = 0; k0 < DIMC; k0 += 64) {
#pragma unroll
    for (int i = 0; i < 4; i++) {
      int id = tid + i * 256;
      int r = id >> 3, c = id & 7;
      f16x8 va = *(const f16x8*)(A + (size_t)(row0 + r) * DIMC + k0 + c * 8);
      f16x8 vb = *(const f16x8*)(B + (size_t)(col0 + r) * DIMC + k0 + c * 8);
      *(f16x8*)(As + r * 64 + ((c ^ (r & 7)) << 3)) = va;
      *(f16x8*)(Bs + r * 64 + ((c ^ (r & 7)) << 3)) = vb;
    }
    __syncthreads();
#pragma unroll
    for (int ks = 0; ks < 2; ++ks) {
      f16x8 af[4], bfr[4];
#pragma unroll
      for (int i = 0; i < 4; i++) {
        int r = wr + i * 16 + l15;
        int c = ks * 4 + l4;
        af[i] = *(const f16x8*)(As + r * 64 + ((c ^ (r & 7)) << 3));
        int r2 = wc + i * 16 + l15;
        bfr[i] = *(const f16x8*)(Bs + r2 * 64 + ((c ^ (r2 & 7)) << 3));
      }
#pragma unroll
      for (int i = 0; i < 4; i++)
#pragma unroll
        for (int j = 0; j < 4; j++) acc[i][j] = mfma16(af[i], bfr[j], acc[i][j]);
    }
    __syncthreads();
  }

#pragma unroll
  for (int i = 0; i < 4; i++) {
#pragma unroll
    for (int j = 0; j < 4; j++) {
      int rowb = row0 + wr + i * 16 + (l4 << 2);
      int col  = col0 + wc + j * 16 + l15;
      if (MODE == 2) {
        float* dst = (float*)dstv;
        float bv = bias[col];
#pragma unroll
        for (int jj = 0; jj < 4; jj++)
          dst[(size_t)(rowb + jj) * DIMC + col] = acc[i][j][jj] + bv;
      } else if (MODE == 0) {
        u16* dst = (u16*)dstv;
        int hh = col >> 6, d = col & 63;
#pragma unroll
        for (int jj = 0; jj < 4; jj++) {
          int row = rowb + jj;
          int bb = row >> 12, n = row & 4095;
          dst[(((size_t)bb * NHEADS + hh) * SEQ + n) * HDIM + d] = f2h_bits(acc[i][j][jj] * scale);
        }
      } else { // MODE 1: V transposed [b][h][d][n]
        u16* dst = (u16*)dstv;
        int hh = col >> 6, d = col & 63;
        int bb = rowb >> 12, nb = rowb & 4095;
        u16x4 pack;
#pragma unroll
        for (int jj = 0; jj < 4; jj++) pack[jj] = f2h_bits(acc[i][j][jj] * scale);
        *(u16x4*)(dst + (((size_t)bb * NHEADS + hh) * HDIM + d) * SEQ + nb) = pack;
      }
    }
  }
}

// ---------------- A: P~ = fp16(exp(min(QK^T,11))) ----------------
// grid (32 qrowtiles, 32 keytiles, nbh), 256 thr. Wave: 32 qrows x 128 keys.
__global__ __launch_bounds__(256) void qk_exp(const u16* __restrict__ Q, const u16* __restrict__ K,
                                              u16* __restrict__ P, int bh0) {
  __shared__ __align__(16) u16 bounce[4][32 * 128];
  const int tid = threadIdx.x, lane = tid & 63, wave = tid >> 6;
  const int l15 = lane & 15, l4 = lane >> 4;
  const size_t bhg = (size_t)bh0 + blockIdx.z;
  const int q0 = blockIdx.x * 128 + wave * 32;
  const int k0 = blockIdx.y * 128;
  const u16* Qh = Q + (bhg * SEQ + q0) * HDIM;
  const u16* Kh = K + (bhg * SEQ + k0) * HDIM;

  f16x8 qf[2][2];   // [16-qrow group][k-half]; Q pre-scaled by 1/8
#pragma unroll
  for (int qr = 0; qr < 2; ++qr)
#pragma unroll
    for (int kh = 0; kh < 2; ++kh)
      qf[qr][kh] = *(const f16x8*)(Qh + (qr * 16 + l15) * HDIM + kh * 32 + l4 * 8);

  u16* bw = bounce[wave];
#pragma unroll 2
  for (int ks = 0; ks < 8; ++ks) {
    const u16* kp = Kh + (size_t)(ks * 16 + l15) * HDIM + l4 * 8;
    f16x8 kf0 = *(const f16x8*)kp;
    f16x8 kf1 = *(const f16x8*)(kp + 32);
#pragma unroll
    for (int qr = 0; qr < 2; ++qr) {
      f32x4 acc = f32x4{0.f, 0.f, 0.f, 0.f};
      acc = mfma16(kf0, qf[qr][0], acc);
      acc = mfma16(kf1, qf[qr][1], acc);
      int row = qr * 16 + l15;
      int gran = ks * 2 + (l4 >> 1);
      u16x4 pack;
#pragma unroll
      for (int j = 0; j < 4; j++) pack[j] = f2h_bits(__expf(fminf(acc[j], 11.0f)));
      *(u16x4*)(bw + row * 128 + ((gran ^ (row & 7)) << 3) + ((l4 & 1) << 2)) = pack;
    }
  }
  __syncthreads();
#pragma unroll
  for (int R = 0; R < 8; ++R) {
    int row = R * 4 + (lane >> 4);
    int gran = lane & 15;
    f16x8 v = *(const f16x8*)(bw + row * 128 + ((gran ^ (row & 7)) << 3));
    *(f16x8*)(P + ((size_t)blockIdx.z * SEQ + q0 + row) * SEQ + k0 + gran * 8) = v;
  }
}

// ---------------- B: fused select + masked PV ----------------
// grid (256 rowtiles, nbh), 512 thr (8 waves); block owns 16 rows.
// Phase1: wave w selects rows 2w, 2w+1 (SWAR binary search -> {t,c*,invZ} in LDS).
// Phase2: wave w covers keys [w*512,(w+1)*512): in-register SWAR mask
//         keep(x,idx) = x >= t + (idx > c*), MFMA PV, LDS f32 partial reduce, invZ.
__global__ __launch_bounds__(512, 4) void pv_select(const u16* __restrict__ P, const u16* __restrict__ Vt,
                                                    u16* __restrict__ Ob, int bh0) {
  __shared__ float Opart[8][16][65];   // 33.3 KB
  __shared__ u32 smeta[16][3];         // {t, c*, invZ}
  const int tid = threadIdx.x, lane = tid & 63, wave = tid >> 6;
  const int l15 = lane & 15, l4 = lane >> 4;
  const int bhl = blockIdx.y;
  const int bhg = bh0 + bhl;
  const int b = bhg / NHEADS, h = bhg - b * NHEADS;
  const int r0 = blockIdx.x * 16;
  const u16* Pbh = P + (size_t)bhl * SEQ * SEQ;
  const u16* Vh  = Vt + (size_t)bhg * HDIM * SEQ;
  const u32 H = 0x80008000u;

  // ---- phase 1: select (2 rows per wave) ----
#pragma unroll 1
  for (int rr = 0; rr < 2; ++rr) {
    const int rloc = wave * 2 + rr;
    const u16* Pr = Pbh + (size_t)(r0 + rloc) * SEQ;
    u32 X[8][4];
#pragma unroll
    for (int cc = 0; cc < 8; ++cc) {
      u32x4 v = *(const u32x4*)(Pr + cc * 512 + lane * 8);
#pragma unroll
      for (int p = 0; p < 4; p++) X[cc][p] = v[p] | H;
    }
    float z = 0.f;
#pragma unroll
    for (int cc = 0; cc < 8; ++cc)
#pragma unroll
      for (int p = 0; p < 4; p++) {
        u32 x = X[cc][p];
        z += h2f_bits((u16)(x & 0x7FFFu));
        z += h2f_bits((u16)((x >> 16) & 0x7FFFu));
      }
    z = wred_add_f32(z);
    float invZ = 1.f / z;
    u32 lo = 0, hi = 0x7FFFu, c1 = 0;
    while (lo < hi) {
      u32 mid = (lo + hi) >> 1;
      u32 M1 = (mid + 1) * 0x10001u;
      u32 pc = 0;
#pragma unroll
      for (int cc = 0; cc < 8; ++cc)
#pragma unroll
        for (int p = 0; p < 4; p++) {
          u32 d = X[cc][p] - M1;
          pc += (d & H) >> 15;
        }
      u32 s = wred_add_u32(pc);
      u32 cnt = (s & 0xFFFFu) + (s >> 16);
      if (cnt < KKEEP) { hi = mid; c1 = cnt; } else lo = mid + 1;
    }
    const u32 t = lo;
    const int r = KKEEP - (int)c1;               // ties kept (>=1)
    const u32 M1t = (t + 1) * 0x10001u;
    const u32 M0t = t * 0x10001u;
    int run = 0; u32 cstar = 0;
    for (int cc = 0; cc < 8; ++cc) {
      u32 eqm[4]; u32 s = 0;
#pragma unroll
      for (int p = 0; p < 4; p++) {
        u32 x = X[cc][p];
        u32 g1 = (x - M1t) & H;
        u32 g0 = (x - M0t) & H;
        eqm[p] = g0 ^ g1;
        s += eqm[p] >> 15;
      }
      int ec = (int)((s & 0xFFFFu) + (s >> 16));
      int inc = ec;
#pragma unroll
      for (int o = 1; o < 64; o <<= 1) { int pf = __shfl_up(inc, o); if (lane >= o) inc += pf; }
      int tot = __shfl(inc, 63);
      if (run + tot >= r) {                      // uniform: boundary chunk
        int need = r - run;
        int local = need - (inc - ec);
        u32 cand = 0xFFFFFFFFu; int cnt2 = 0;
#pragma unroll
        for (int p = 0; p < 4; p++)
#pragma unroll
          for (int half = 0; half < 2; half++) {
            u32 eq = half ? (eqm[p] >> 31) : ((eqm[p] >> 15) & 1u);
            if (eq) { cnt2++; if (cnt2 == local) cand = (u32)(cc * 512 + lane * 8 + p * 2 + half); }
          }
        cstar = wred_min_u32(cand);
        break;
      }
      run += tot;
    }
    if (lane == 0) {
      smeta[rloc][0] = t;
      smeta[rloc][1] = cstar;
      smeta[rloc][2] = __builtin_bit_cast(u32, invZ);
    }
  }
  __syncthreads();

  // ---- phase 2: masked PV over keys [wave*512, (wave+1)*512) ----
  const u32 t = smeta[l15][0];
  const int cstar = (int)smeta[l15][1];
  const u32 Mt = t * 0x10001u;
  const u16* Prow = Pbh + (size_t)(r0 + l15) * SEQ + wave * 512 + l4 * 8;
  f32x4 acc[4];
#pragma unroll
  for (int ds = 0; ds < 4; ds++) acc[ds] = f32x4{0.f, 0.f, 0.f, 0.f};
#pragma unroll 2
  for (int kb = 0; kb < 512; kb += 32) {
    u32x4 praw = *(const u32x4*)(Prow + kb);
    int base = cstar - (wave * 512 + kb + l4 * 8);
    u32x4 om;
#pragma unroll
    for (int p = 0; p < 4; ++p) {
      u32 s0 = (u32)(base - 2 * p) >> 31;        // idx0 > c*
      u32 s1 = (u32)(base - 2 * p - 1) >> 31;    // idx1 > c*
      u32 M1 = Mt + s0 + (s1 << 16);
      u32 d  = (praw[p] | H) - M1;
      u32 g  = d & H;                             // x >= t + pos
      u32 m  = g | (g - (g >> 15));
      om[p]  = praw[p] & m;
    }
    f16x8 pb = __builtin_bit_cast(f16x8, om);
#pragma unroll
    for (int ds = 0; ds < 4; ++ds) {
      f16x8 af = *(const f16x8*)(Vh + (size_t)(ds * 16 + l15) * SEQ + wave * 512 + kb + l4 * 8);
      acc[ds] = mfma16(af, pb, acc[ds]);          // D[vdim][prow], col l15 = prow
    }
  }
  // partials: Opart[wave][prow][vdim]
#pragma unroll
  for (int ds = 0; ds < 4; ++ds)
#pragma unroll
    for (int j = 0; j < 4; j++)
      Opart[wave][l15][ds * 16 + l4 * 4 + j] = acc[ds][j];
  __syncthreads();
  // reduce 8 partials + invZ; 1024 outputs over 512 threads
#pragma unroll
  for (int i = tid; i < 16 * 64; i += 512) {
    int row = i >> 6, d = i & 63;
    float v = 0.f;
#pragma unroll
    for (int w = 0; w < 8; ++w) v += Opart[w][row][d];
    v *= __builtin_bit_cast(float, smeta[row][2]);
    Ob[((size_t)b * SEQ + r0 + row) * DIMC + h * HDIM + d] = f2h_bits(v);
  }
}

// ---------------- launch ----------------
extern "C" void kernel_launch(void* const* d_in, const int* in_sizes, int n_in,
                              void* d_out, int out_size, void* d_ws, size_t ws_size,
                              hipStream_t stream) {
  const float* x  = (const float*)d_in[0];
  const float* Wq = (const float*)d_in[1];
  const float* Wk = (const float*)d_in[2];
  const float* Wv = (const float*)d_in[3];
  const float* Wp = (const float*)d_in[4];
  const float* bp = (const float*)d_in[5];
  float* out = (float*)d_out;

  const size_t M = 2 * (size_t)SEQ;            // 8192
  const size_t XB = M * DIMC * 2;
  const size_t WB = (size_t)DIMC * DIMC * 2;
  const size_t NBH = 2 * NHEADS;               // 24

  char* w = (char*)d_ws;
  u16* xb   = (u16*)w; w += XB;
  u16* Wqb  = (u16*)w; w += WB;
  u16* Wkb  = (u16*)w; w += WB;
  u16* Wvb  = (u16*)w; w += WB;
  u16* Wpb  = (u16*)w; w += WB;
  u16* Qb   = (u16*)w; w += XB;
  u16* Kbuf = (u16*)w; w += XB;
  u16* Vtb  = (u16*)w; w += XB;
  u16* Obuf = (u16*)w; w += XB;
  u16* Pbuf = (u16*)w;

  size_t used  = (size_t)(w - (char*)d_ws);
  size_t avail = ws_size > used ? ws_size - used : 0;
  const size_t perBh = (size_t)SEQ * SEQ * 2;  // 33.55 MB
  int chunk = (int)(avail / perBh);
  if (chunk > (int)NBH) chunk = (int)NBH;
  if (chunk < 1) chunk = 1;

  cast_f32_to_f16<<<6144, 256, 0, stream>>>(x,  xb,  (int)(M * DIMC / 4));
  cast_f32_to_f16<<<576,  256, 0, stream>>>(Wq, Wqb, (int)(WB / 8));
  cast_f32_to_f16<<<576,  256, 0, stream>>>(Wk, Wkb, (int)(WB / 8));
  cast_f32_to_f16<<<576,  256, 0, stream>>>(Wv, Wvb, (int)(WB / 8));
  cast_f32_to_f16<<<576,  256, 0, stream>>>(Wp, Wpb, (int)(WB / 8));

  dim3 gg(64, 6);
  gemm_nt<0><<<gg, 256, 0, stream>>>(xb, Wqb, 0.125f, nullptr, Qb);    // Q pre-scaled
  gemm_nt<0><<<gg, 256, 0, stream>>>(xb, Wkb, 1.0f,   nullptr, Kbuf);
  gemm_nt<1><<<gg, 256, 0, stream>>>(xb, Wvb, 1.0f,   nullptr, Vtb);   // V transposed

  for (int bh0 = 0; bh0 < (int)NBH; bh0 += chunk) {
    int nb = (int)NBH - bh0; if (nb > chunk) nb = chunk;
    qk_exp   <<<dim3(32, 32, nb), 256, 0, stream>>>(Qb, Kbuf, Pbuf, bh0);
    pv_select<<<dim3(256, nb),    512, 0, stream>>>(Pbuf, Vtb, Obuf, bh0);
  }

  gemm_nt<2><<<gg, 256, 0, stream>>>(Obuf, Wpb, 1.0f, bp, out);
}